// Round 8
// baseline (140.618 us; speedup 1.0000x reference)
//
#include <hip/hip_runtime.h>
#include <hip/hip_bf16.h>
#include <math.h>

// Problem constants
#define SEQ 4096
#define DM  1024
#define NIMU 72
#define NNOISE 12
#define NJ (NIMU*NNOISE)     // 864
#define TSTEPS 300
#define PLANE (NIMU*SEQ)     // 294912

// R14 fragment-linear layouts (32x32x16 bf16 MFMA granules):
//   granule(tile, ch) = 512 shorts (1KB); lane l holds 8 shorts at +l*8:
//     row/col = l&31, k = ch*16 + (l>>5)*8 + 0..7
//   ch 0..63 = hi half (k 0..1023), ch 64..127 = lo half.
// A2f : 128 s_tiles x 128 ch x 512 shorts = 16.78 MB
// Btf : 28  j_tiles x 128 ch x 512 shorts =  3.67 MB (tile 27 = pad, never written)
// ptA/ptB : 12 x PLANE f32 split-K partials (14.16 MB each)
#define A2F_SHORTS ((size_t)128 * 128 * 512)
#define BTF_SHORTS ((size_t)28 * 128 * 512)

typedef __attribute__((ext_vector_type(8))) short bf16x8;
typedef __attribute__((ext_vector_type(16))) float f32x16;
typedef __attribute__((ext_vector_type(4))) float f32x4;
typedef __attribute__((ext_vector_type(2))) float f32x2;

__device__ __forceinline__ float softplus_f(float x) {
    return fmaxf(x, 0.f) + log1pf(expf(-fabsf(x)));
}

// round-to-nearest-even bf16 split: x ~= hi + lo with |err| ~ 2^-16 * |x|
__device__ __forceinline__ void split_bf16(float x, short& hi, short& lo) {
    unsigned b = __float_as_uint(x);
    unsigned h = (b + 0x7FFFu + ((b >> 16) & 1u)) >> 16;
    float hf = __uint_as_float(h << 16);
    float r = x - hf;
    unsigned b2 = __float_as_uint(r);
    unsigned l2 = (b2 + 0x7FFFu + ((b2 >> 16) & 1u)) >> 16;
    hi = (short)h;
    lo = (short)l2;
}

// async global->LDS, 16B per lane: dst = wave-uniform LDS base (+lane*16 by HW),
// src = per-lane global address.
__device__ __forceinline__ void gload_lds16(const void* g, void* l) {
    __builtin_amdgcn_global_load_lds(
        (const __attribute__((address_space(1))) unsigned int*)g,
        (__attribute__((address_space(3))) unsigned int*)l,
        16, 0, 0);
}

// ---------------- 1. LayerNorm -> A2f (32-row granules, bf16 hi|lo) ----------------
__global__ __launch_bounds__(512) void ln_kernel(const float* __restrict__ x,
                                                 const float* __restrict__ gamma,
                                                 const float* __restrict__ beta,
                                                 short* __restrict__ A2f) {
    const int tid = threadIdx.x;
    const int row = blockIdx.x * 16 + (tid >> 5);
    const int c   = tid & 31;
    const float4* xr = (const float4*)(x + (size_t)row * DM);

    float s = 0.f, sq = 0.f;
    #pragma unroll
    for (int i = 0; i < 8; ++i) {
        float4 v = xr[c + 32 * i];
        s  += v.x + v.y + v.z + v.w;
        sq += v.x*v.x + v.y*v.y + v.z*v.z + v.w*v.w;
    }
    #pragma unroll
    for (int off = 1; off < 32; off <<= 1) {     // 32-lane row groups within wave
        s  += __shfl_xor(s, off);
        sq += __shfl_xor(sq, off);
    }
    const float mean = s * (1.f / DM);
    const float var  = sq * (1.f / DM) - mean * mean;
    const float rstd = rsqrtf(fmaxf(var, 0.f) + 1e-5f);

    const int s_tile = row >> 5, r = row & 31;
    #pragma unroll
    for (int i = 0; i < 8; ++i) {
        const int c4 = c + 32 * i;               // float4 column 0..255, k = 4*c4..+3
        float4 v  = xr[c4];
        float4 gm = ((const float4*)gamma)[c4];
        float4 bt = ((const float4*)beta)[c4];
        float o[4];
        o[0] = (v.x - mean) * rstd * gm.x + bt.x;
        o[1] = (v.y - mean) * rstd * gm.y + bt.y;
        o[2] = (v.z - mean) * rstd * gm.z + bt.z;
        o[3] = (v.w - mean) * rstd * gm.w + bt.w;
        short4 hv, lv;
        split_bf16(o[0], hv.x, lv.x);
        split_bf16(o[1], hv.y, lv.y);
        split_bf16(o[2], hv.z, lv.z);
        split_bf16(o[3], hv.w, lv.w);
        const int ch = c4 >> 2;                  // 16-k chunk
        const int g  = (c4 >> 1) & 1;            // 8-k group within chunk
        const int o4 = (c4 & 1) * 4;             // short offset within group
        const size_t base = ((size_t)s_tile * 128 + ch) * 512 + (g * 32 + r) * 8 + o4;
        *(short4*)(A2f + base)                    = hv;   // hi: ch
        *(short4*)(A2f + base + (size_t)64 * 512) = lv;   // lo: ch+64
    }
}

// ---------------- 2a. W -> Btf (transpose + split, 32-col granules) ----------------
__global__ __launch_bounds__(256) void wprep_kernel(const float* __restrict__ W,
                                                    short* __restrict__ Btf) {
    __shared__ float T[32][33];
    const int k0 = blockIdx.x * 32, j0 = blockIdx.y * 32;
    const int t = threadIdx.x;
    {
        const int r = t >> 3, c4 = (t & 7) * 4;
        float4 v = *(const float4*)(W + (size_t)(k0 + r) * NJ + j0 + c4);
        T[r][c4 + 0] = v.x; T[r][c4 + 1] = v.y; T[r][c4 + 2] = v.z; T[r][c4 + 3] = v.w;
    }
    __syncthreads();
    if (t < 128) {
        const int q = t >> 6;                    // which 16-k chunk of the 32
        const int l = t & 63;
        const int n = l & 31, g = l >> 5;
        const int jt = blockIdx.y;               // j_tile (32 cols)
        const int ch = blockIdx.x * 2 + q;
        bf16x8 hv, lv;
        #pragma unroll
        for (int o = 0; o < 8; ++o) {
            short h, lo_;
            split_bf16(T[q * 16 + g * 8 + o][n], h, lo_);
            hv[o] = h; lv[o] = lo_;
        }
        short* dh = Btf + ((size_t)jt * 128 + ch) * 512 + l * 8;
        *(bf16x8*)dh = hv;
        *(bf16x8*)(dh + (size_t)64 * 512) = lv;  // lo chunk = ch+64
    }
}

// ---------------- 2b. LDS-staged MFMA GEMM, counted-vmcnt pipeline ----------------
// R15: 2-phase loop drains vmcnt(0) at every __syncthreads -> 16 exposed HBM/L2
// latency stalls (A2f is cold HBM ~900cyc) where ALL waves of the block wait.
// R16 (T3/T4): BK=16 (1 ch/iter, 16 granules), 4 LDS buffers (64 KB), stage 3
// tiles ahead. Per iter: s_waitcnt vmcnt(8) (own outstanding = 3 tiles x 4 loads;
// wait oldest tile only) -> raw s_barrier -> sched_barrier(0) -> issue stage(it+3)
// -> 8 ds_read + 12 MFMA. Loads stay in flight ACROSS barriers; never drain to 0
// in steady state (only last 2 iters: vmcnt 4 -> 0). Overwrite safety: stage(it+3)
// writes buf[(it-1)&3], whose readers all passed this iter's barrier.
// Occupancy 2 blocks/CU (128 KB LDS). Epilogue/split-K unchanged.
__global__ __launch_bounds__(256, 2) void gemm_kernel(const short* __restrict__ A2f,
                                                      const short* __restrict__ Btf,
                                                      const float* __restrict__ bias,
                                                      float* __restrict__ ptA,
                                                      float* __restrict__ ptB) {
    // lds[buf][slot][lane]: slots 0..7 = A granules (tt*2+part), 8..15 = B granules.
    __shared__ bf16x8 lds[4][16][64];            // 64 KB

    const int bid = blockIdx.x;
    const int c = bid & 7, u = bid >> 3;         // c = XCD, u 0..55
    const int kh = u / 28, v = u - kh * 28;      // kh = K-half
    const int bxi = v / 7, by = v - bxi * 7;     // bxi 0..3, by 0..6
    const int bx = c * 4 + bxi;                  // 0..31
    const int l = threadIdx.x & 63, w = threadIdx.x >> 6;
    const int bx4 = bx * 4, by4 = by * 4;        // block tile bases (32-granule units)
    const int mt0 = bx4 + (w & 1) * 2;           // wave's m-tile base
    const int jt0 = by4 + (w >> 1) * 2;          // wave's j-tile base
    const int ch0 = kh * 32;                     // 16-k chunks; half = 32 chunks

    // staging: wave w stages slots w*4 .. w*4+3 (waves 0,1 = A; 2,3 = B)
    auto stage = [&](int buf, int it) {
        const int ch = ch0 + it;
        #pragma unroll
        for (int i = 0; i < 4; ++i) {
            const int slot = w * 4 + i;
            const short* src;
            if (slot < 8) {
                const int tt = slot >> 1, part = slot & 1;
                src = A2f + ((size_t)(bx4 + tt) * 128 + ch + part * 64) * 512 + l * 8;
            } else {
                const int tt = (slot - 8) >> 1, part = slot & 1;
                src = Btf + ((size_t)(by4 + tt) * 128 + ch + part * 64) * 512 + l * 8;
            }
            gload_lds16(src, &lds[buf][slot][0]);
        }
    };

    f32x16 acc[2][2] = {};
    const int wa = (w & 1) * 2;                  // wave's A tile base (local)
    const int wb = (w >> 1) * 2;                 // wave's B tile base (local)

    auto compute = [&](int cur) {
        bf16x8 a0h = lds[cur][(wa + 0) * 2 + 0][l];
        bf16x8 a0l = lds[cur][(wa + 0) * 2 + 1][l];
        bf16x8 a1h = lds[cur][(wa + 1) * 2 + 0][l];
        bf16x8 a1l = lds[cur][(wa + 1) * 2 + 1][l];
        bf16x8 b0h = lds[cur][8 + (wb + 0) * 2 + 0][l];
        bf16x8 b0l = lds[cur][8 + (wb + 0) * 2 + 1][l];
        bf16x8 b1h = lds[cur][8 + (wb + 1) * 2 + 0][l];
        bf16x8 b1l = lds[cur][8 + (wb + 1) * 2 + 1][l];
        acc[0][0] = __builtin_amdgcn_mfma_f32_32x32x16_bf16(a0h, b0h, acc[0][0], 0, 0, 0);
        acc[0][1] = __builtin_amdgcn_mfma_f32_32x32x16_bf16(a0h, b1h, acc[0][1], 0, 0, 0);
        acc[1][0] = __builtin_amdgcn_mfma_f32_32x32x16_bf16(a1h, b0h, acc[1][0], 0, 0, 0);
        acc[1][1] = __builtin_amdgcn_mfma_f32_32x32x16_bf16(a1h, b1h, acc[1][1], 0, 0, 0);
        acc[0][0] = __builtin_amdgcn_mfma_f32_32x32x16_bf16(a0h, b0l, acc[0][0], 0, 0, 0);
        acc[0][1] = __builtin_amdgcn_mfma_f32_32x32x16_bf16(a0h, b1l, acc[0][1], 0, 0, 0);
        acc[1][0] = __builtin_amdgcn_mfma_f32_32x32x16_bf16(a1h, b0l, acc[1][0], 0, 0, 0);
        acc[1][1] = __builtin_amdgcn_mfma_f32_32x32x16_bf16(a1h, b1l, acc[1][1], 0, 0, 0);
        acc[0][0] = __builtin_amdgcn_mfma_f32_32x32x16_bf16(a0l, b0h, acc[0][0], 0, 0, 0);
        acc[0][1] = __builtin_amdgcn_mfma_f32_32x32x16_bf16(a0l, b1h, acc[0][1], 0, 0, 0);
        acc[1][0] = __builtin_amdgcn_mfma_f32_32x32x16_bf16(a1l, b0h, acc[1][0], 0, 0, 0);
        acc[1][1] = __builtin_amdgcn_mfma_f32_32x32x16_bf16(a1l, b1h, acc[1][1], 0, 0, 0);
    };

    stage(0, 0); stage(1, 1); stage(2, 2);       // prologue: 3 tiles in flight (12 loads)

    #pragma unroll 1
    for (int it = 0; it < 30; ++it) {
        // own outstanding = tiles it, it+1, it+2 (12 loads); wait oldest 4 done
        asm volatile("s_waitcnt vmcnt(8)" ::: "memory");
        __builtin_amdgcn_s_barrier();
        __builtin_amdgcn_sched_barrier(0);
        if (it + 3 < 32) stage((it + 3) & 3, it + 3);
        compute(it & 3);
    }
    asm volatile("s_waitcnt vmcnt(4)" ::: "memory");   // it=30: tiles 30,31 in flight
    __builtin_amdgcn_s_barrier();
    __builtin_amdgcn_sched_barrier(0);
    compute(30 & 3);
    asm volatile("s_waitcnt vmcnt(0)" ::: "memory");   // it=31: tile 31
    __builtin_amdgcn_s_barrier();
    __builtin_amdgcn_sched_barrier(0);
    compute(31 & 3);

    // epilogue: 32x32 C/D layout col=lane&31 (j), row=(reg&3)+8*(reg>>2)+4*(lane>>5)
    float* ptH = kh ? ptB : ptA;
    const int jn = l & 31, hi5 = l >> 5;
    #pragma unroll
    for (int ni = 0; ni < 2; ++ni) {
        const int jt = jt0 + ni;
        if (jt < 27) {                            // tile 27 = pad, fully masked
            const int j = jt * 32 + jn;
            const float bj = (kh == 0) ? bias[j] : 0.f;
            #pragma unroll
            for (int mi = 0; mi < 2; ++mi) {
                #pragma unroll
                for (int q = 0; q < 4; ++q) {     // reg quad q -> rows q*8+hi5*4+0..3
                    f32x4 o;
                    o[0] = acc[mi][ni][q * 4 + 0] + bj;
                    o[1] = acc[mi][ni][q * 4 + 1] + bj;
                    o[2] = acc[mi][ni][q * 4 + 2] + bj;
                    o[3] = acc[mi][ni][q * 4 + 3] + bj;
                    const int s = (mt0 + mi) * 32 + q * 8 + hi5 * 4;
                    *(f32x4*)(ptH + (size_t)j * SEQ + s) = o;
                }
            }
        }
    }
}

// ---------------- 3. Spring recurrence + LDS-window scatter + fused tail ----------------
// R11 structure (3-parity buffers, 1 lgkm wait per 3 macro-steps) unchanged.
// R16: tail_kernel fused in -- this block's (s0+tid, imu) coordinates cover exactly
// 4 output elements of planes 1..4 (noise 8..11); removes a launch + gap.
__global__ __launch_bounds__(256) void spring_kernel(const float* __restrict__ ptA,
                                                     const float* __restrict__ ptB,
                                                     float* __restrict__ out) {
    __shared__ float w3[3][4 * 368];           // 363 used per wave per parity
    const int tid  = threadIdx.x;
    const int lane = tid & 63;
    const int wid  = tid >> 6;
    const int s0   = blockIdx.x * 256;
    const int imu  = blockIdx.y;
    const int s    = s0 + tid;

    // zero own windows (wave-private: no barrier needed before main loop)
    #pragma unroll
    for (int b = 0; b < 3; ++b)
        #pragma unroll
        for (int i = 0; i < 6; ++i) {
            const int idx = lane + i * 64;
            if (idx < 363) w3[b][wid * 368 + idx] = 0.f;
        }

    const int base = imu * SEQ + s;
    const float p0  = ptA[(size_t)0 * PLANE + base] + ptB[(size_t)0 * PLANE + base];
    const float p1  = ptA[(size_t)1 * PLANE + base] + ptB[(size_t)1 * PLANE + base];
    const float p2  = ptA[(size_t)2 * PLANE + base] + ptB[(size_t)2 * PLANE + base];
    const float p3  = ptA[(size_t)3 * PLANE + base] + ptB[(size_t)3 * PLANE + base];
    const float c1  = ptA[(size_t)4 * PLANE + base] + ptB[(size_t)4 * PLANE + base];
    const float c2  = ptA[(size_t)5 * PLANE + base] + ptB[(size_t)5 * PLANE + base];
    const float ph1 = ptA[(size_t)6 * PLANE + base] + ptB[(size_t)6 * PLANE + base];
    const float ph2 = ptA[(size_t)7 * PLANE + base] + ptB[(size_t)7 * PLANE + base];

    float dd = softplus_f(p1);
    float kk = dd * dd * 0.25f + softplus_f(p0);
    float om1 = 0.5f * sqrtf(fmaxf(4.f * kk - dd * dd, 0.f));
    float dt = softplus_f(p3);
    float kt = dt * dt * 0.25f + softplus_f(p2);
    float om2 = 0.5f * sqrtf(fmaxf(4.f * kt - dt * dt, 0.f));
    float e1 = expf(-0.5f * dd), e2 = expf(-0.5f * dt);
    float sn, cs, sn2, cs2;
    sincosf(om1, &sn, &cs);
    sincosf(om2, &sn2, &cs2);
    f32x2 Rr = {e1 * cs, e2 * cs2};          // per-step rotation (packed: osc1, osc2)
    f32x2 Ri = {e1 * sn, e2 * sn2};
    sincosf(ph1, &sn, &cs);
    sincosf(ph2, &sn2, &cs2);
    f32x2 zr = {c1 * cs, c2 * cs2};          // stream A state (t = 0)
    f32x2 zi = {c1 * sn, c2 * sn2};

    // stream B state: z * R^150 (exp-by-squaring)
    f32x2 zrB, ziB;
    {
        f32x2 prr = Rr, pri = Ri;
        f32x2 qr = {1.f, 1.f}, qi = {0.f, 0.f};
        int e = 150;
        while (e) {
            if (e & 1) {
                f32x2 nr = qr * prr - qi * pri;
                qi = qr * pri + qi * prr;
                qr = nr;
            }
            f32x2 nr = prr * prr - pri * pri;
            pri = 2.f * prr * pri;
            prr = nr;
            e >>= 1;
        }
        f32x2 nr = zr * qr - zi * qi;
        ziB = zr * qi + zi * qr;
        zrB = nr;
    }

    float* q0 = &w3[0][wid * 368 + lane];
    float* q1 = &w3[1][wid * 368 + lane];
    float* q2 = &w3[2][wid * 368 + lane];

    #pragma unroll 1
    for (int j = 0; j < 150; j += 3) {
        // values for macro-steps j, j+1, j+2 on both streams
        float vA0 = zi.x + zi.y;
        { f32x2 nr = zr * Rr - zi * Ri; zi = zr * Ri + zi * Rr; zr = nr; }
        float vA1 = zi.x + zi.y;
        { f32x2 nr = zr * Rr - zi * Ri; zi = zr * Ri + zi * Rr; zr = nr; }
        float vA2 = zi.x + zi.y;
        { f32x2 nr = zr * Rr - zi * Ri; zi = zr * Ri + zi * Rr; zr = nr; }
        float vB0 = ziB.x + ziB.y;
        { f32x2 nr = zrB * Rr - ziB * Ri; ziB = zrB * Ri + ziB * Rr; zrB = nr; }
        float vB1 = ziB.x + ziB.y;
        { f32x2 nr = zrB * Rr - ziB * Ri; ziB = zrB * Ri + ziB * Rr; zrB = nr; }
        float vB2 = ziB.x + ziB.y;
        { f32x2 nr = zrB * Rr - ziB * Ri; ziB = zrB * Ri + ziB * Rr; zrB = nr; }

        // all 6 reads issue together -> single lgkm wait per group
        const float a0 = q0[j],     b0 = q0[j + 150];
        const float a1 = q1[j + 1], b1 = q1[j + 151];
        const float a2 = q2[j + 2], b2 = q2[j + 152];
        q0[j]       = a0 + vA0;  q0[j + 150] = b0 + vB0;
        q1[j + 1]   = a1 + vA1;  q1[j + 151] = b1 + vB1;
        q2[j + 2]   = a2 + vA2;  q2[j + 152] = b2 + vB2;
        __asm__ volatile("" ::: "memory");   // pin group order (cross-lane RAW, dist 3)
    }

    // fused tail: noise planes 8..11 -> out planes 1..4 (softplus on odd noise)
    #pragma unroll
    for (int np = 0; np < 4; ++np) {
        float v = ptA[(size_t)(8 + np) * PLANE + base]
                + ptB[(size_t)(8 + np) * PLANE + base];
        if (np & 1) v = softplus_f(v);
        out[(size_t)(np + 1) * PLANE + base] = v;
    }

    __syncthreads();
    // merge 3 parities x 4 wave windows + masked global flush
    for (int i = tid; i < 555; i += 256) {
        float sum = 0.f;
        #pragma unroll
        for (int w = 0; w < 4; ++w) {
            const int idx = i - (w << 6);
            if (idx >= 0 && idx < 363) {
                const int o = w * 368 + idx;
                sum += w3[0][o] + w3[1][o] + w3[2][o];
            }
        }
        const int pos = s0 + i;
        if (pos < SEQ) {
            (void)__hip_atomic_fetch_add(&out[(size_t)imu * SEQ + pos], sum,
                                         __ATOMIC_RELAXED, __HIP_MEMORY_SCOPE_AGENT);
        }
    }
}

extern "C" void kernel_launch(void* const* d_in, const int* in_sizes, int n_in,
                              void* d_out, int out_size, void* d_ws, size_t ws_size,
                              hipStream_t stream) {
    const float* hs    = (const float*)d_in[0];
    const float* gamma = (const float*)d_in[1];
    const float* beta  = (const float*)d_in[2];
    const float* W     = (const float*)d_in[3];
    const float* b     = (const float*)d_in[4];
    float* out = (float*)d_out;

    short* A2f = (short*)d_ws;                        // 16.78 MB
    short* Btf = A2f + A2F_SHORTS;                    //  3.67 MB
    float* ptA = (float*)(Btf + BTF_SHORTS);          // 14.16 MB (split-K half 0 + bias)
    float* ptB = ptA + (size_t)12 * PLANE;            // 14.16 MB (split-K half 1)

    hipMemsetAsync(out, 0, (size_t)PLANE * sizeof(float), stream);

    ln_kernel<<<SEQ / 16, 512, 0, stream>>>(hs, gamma, beta, A2f);
    wprep_kernel<<<dim3(DM / 32, NJ / 32), 256, 0, stream>>>(W, Btf);
    gemm_kernel<<<448, 256, 0, stream>>>(A2f, Btf, b, ptA, ptB);
    spring_kernel<<<dim3(SEQ / 256, NIMU), 256, 0, stream>>>(ptA, ptB, out);
}

// Round 9
// 137.007 us; speedup vs baseline: 1.0264x; 1.0264x over previous
//
#include <hip/hip_runtime.h>
#include <hip/hip_bf16.h>
#include <math.h>

// Problem constants
#define SEQ 4096
#define DM  1024
#define NIMU 72
#define NNOISE 12
#define NJ (NIMU*NNOISE)     // 864
#define TSTEPS 300
#define PLANE (NIMU*SEQ)     // 294912

// R14 fragment-linear layouts (32x32x16 bf16 MFMA granules):
//   granule(tile, ch) = 512 shorts (1KB); lane l holds 8 shorts at +l*8:
//     row/col = l&31, k = ch*16 + (l>>5)*8 + 0..7
//   ch 0..63 = hi half (k 0..1023), ch 64..127 = lo half.
// A2f : 128 s_tiles x 128 ch x 512 shorts = 16.78 MB
// Btf : 28  j_tiles x 128 ch x 512 shorts =  3.67 MB (tile 27 = pad, never written)
// ptA/ptB : 12 x PLANE f32 split-K partials (14.16 MB each)
#define A2F_SHORTS ((size_t)128 * 128 * 512)
#define BTF_SHORTS ((size_t)28 * 128 * 512)

typedef __attribute__((ext_vector_type(8))) short bf16x8;
typedef __attribute__((ext_vector_type(16))) float f32x16;
typedef __attribute__((ext_vector_type(4))) float f32x4;
typedef __attribute__((ext_vector_type(2))) float f32x2;

__device__ __forceinline__ float softplus_f(float x) {
    return fmaxf(x, 0.f) + log1pf(expf(-fabsf(x)));
}

// round-to-nearest-even bf16 split: x ~= hi + lo with |err| ~ 2^-16 * |x|
__device__ __forceinline__ void split_bf16(float x, short& hi, short& lo) {
    unsigned b = __float_as_uint(x);
    unsigned h = (b + 0x7FFFu + ((b >> 16) & 1u)) >> 16;
    float hf = __uint_as_float(h << 16);
    float r = x - hf;
    unsigned b2 = __float_as_uint(r);
    unsigned l2 = (b2 + 0x7FFFu + ((b2 >> 16) & 1u)) >> 16;
    hi = (short)h;
    lo = (short)l2;
}

// async global->LDS, 16B per lane: dst = wave-uniform LDS base (+lane*16 by HW),
// src = per-lane global address.
__device__ __forceinline__ void gload_lds16(const void* g, void* l) {
    __builtin_amdgcn_global_load_lds(
        (const __attribute__((address_space(1))) unsigned int*)g,
        (__attribute__((address_space(3))) unsigned int*)l,
        16, 0, 0);
}

// ---------------- 1. LayerNorm -> A2f (32-row granules, bf16 hi|lo) ----------------
__global__ __launch_bounds__(512) void ln_kernel(const float* __restrict__ x,
                                                 const float* __restrict__ gamma,
                                                 const float* __restrict__ beta,
                                                 short* __restrict__ A2f) {
    const int tid = threadIdx.x;
    const int row = blockIdx.x * 16 + (tid >> 5);
    const int c   = tid & 31;
    const float4* xr = (const float4*)(x + (size_t)row * DM);

    float s = 0.f, sq = 0.f;
    #pragma unroll
    for (int i = 0; i < 8; ++i) {
        float4 v = xr[c + 32 * i];
        s  += v.x + v.y + v.z + v.w;
        sq += v.x*v.x + v.y*v.y + v.z*v.z + v.w*v.w;
    }
    #pragma unroll
    for (int off = 1; off < 32; off <<= 1) {     // 32-lane row groups within wave
        s  += __shfl_xor(s, off);
        sq += __shfl_xor(sq, off);
    }
    const float mean = s * (1.f / DM);
    const float var  = sq * (1.f / DM) - mean * mean;
    const float rstd = rsqrtf(fmaxf(var, 0.f) + 1e-5f);

    const int s_tile = row >> 5, r = row & 31;
    #pragma unroll
    for (int i = 0; i < 8; ++i) {
        const int c4 = c + 32 * i;               // float4 column 0..255, k = 4*c4..+3
        float4 v  = xr[c4];
        float4 gm = ((const float4*)gamma)[c4];
        float4 bt = ((const float4*)beta)[c4];
        float o[4];
        o[0] = (v.x - mean) * rstd * gm.x + bt.x;
        o[1] = (v.y - mean) * rstd * gm.y + bt.y;
        o[2] = (v.z - mean) * rstd * gm.z + bt.z;
        o[3] = (v.w - mean) * rstd * gm.w + bt.w;
        short4 hv, lv;
        split_bf16(o[0], hv.x, lv.x);
        split_bf16(o[1], hv.y, lv.y);
        split_bf16(o[2], hv.z, lv.z);
        split_bf16(o[3], hv.w, lv.w);
        const int ch = c4 >> 2;                  // 16-k chunk
        const int g  = (c4 >> 1) & 1;            // 8-k group within chunk
        const int o4 = (c4 & 1) * 4;             // short offset within group
        const size_t base = ((size_t)s_tile * 128 + ch) * 512 + (g * 32 + r) * 8 + o4;
        *(short4*)(A2f + base)                    = hv;   // hi: ch
        *(short4*)(A2f + base + (size_t)64 * 512) = lv;   // lo: ch+64
    }
}

// ---------------- 2a. W -> Btf (transpose + split, 32-col granules) ----------------
__global__ __launch_bounds__(256) void wprep_kernel(const float* __restrict__ W,
                                                    short* __restrict__ Btf) {
    __shared__ float T[32][33];
    const int k0 = blockIdx.x * 32, j0 = blockIdx.y * 32;
    const int t = threadIdx.x;
    {
        const int r = t >> 3, c4 = (t & 7) * 4;
        float4 v = *(const float4*)(W + (size_t)(k0 + r) * NJ + j0 + c4);
        T[r][c4 + 0] = v.x; T[r][c4 + 1] = v.y; T[r][c4 + 2] = v.z; T[r][c4 + 3] = v.w;
    }
    __syncthreads();
    if (t < 128) {
        const int q = t >> 6;                    // which 16-k chunk of the 32
        const int l = t & 63;
        const int n = l & 31, g = l >> 5;
        const int jt = blockIdx.y;               // j_tile (32 cols)
        const int ch = blockIdx.x * 2 + q;
        bf16x8 hv, lv;
        #pragma unroll
        for (int o = 0; o < 8; ++o) {
            short h, lo_;
            split_bf16(T[q * 16 + g * 8 + o][n], h, lo_);
            hv[o] = h; lv[o] = lo_;
        }
        short* dh = Btf + ((size_t)jt * 128 + ch) * 512 + l * 8;
        *(bf16x8*)dh = hv;
        *(bf16x8*)(dh + (size_t)64 * 512) = lv;  // lo chunk = ch+64
    }
}

// ---------------- 2b. LDS-staged MFMA GEMM, 32x32x16, split-K=2 ----------------
// R16 post-mortem: counted-vmcnt graft FAILED (+4us) -- compiler inserts its own
// vmcnt(0) before the first ds_read (it tracks global_load_lds as an LDS writer),
// so the pipeline drained anyway and we paid 2x barriers + sched_barrier handcuffs.
// R17: revert to the R15 2-phase structure (proven in the 138.7 best): BK=32k
// (2 ch/iter, 16 iters), 2 LDS buffers (64 KB), stage(it+1) -> compute(it) ->
// __syncthreads. 2 blocks/CU. Epilogue/split-K unchanged.
__global__ __launch_bounds__(256, 2) void gemm_kernel(const short* __restrict__ A2f,
                                                      const short* __restrict__ Btf,
                                                      const float* __restrict__ bias,
                                                      float* __restrict__ ptA,
                                                      float* __restrict__ ptB) {
    // lds[buf][G][lane]: G = ch_local*16 + (g<8 ? A granule g : B granule g-8+8)
    __shared__ bf16x8 lds[2][32][64];            // 64 KB

    const int bid = blockIdx.x;
    const int c = bid & 7, u = bid >> 3;         // c = XCD, u 0..55
    const int kh = u / 28, v = u - kh * 28;      // kh = K-half
    const int bxi = v / 7, by = v - bxi * 7;     // bxi 0..3, by 0..6
    const int bx = c * 4 + bxi;                  // 0..31
    const int l = threadIdx.x & 63, w = threadIdx.x >> 6;
    const int bx4 = bx * 4, by4 = by * 4;        // block tile bases (32-granule units)
    const int mt0 = bx4 + (w & 1) * 2;           // wave's m-tile base
    const int jt0 = by4 + (w >> 1) * 2;          // wave's j-tile base
    const int ch0 = kh * 32;                     // 16-k chunks; half = 32 chunks

    // staging role (wave-uniform)
    const int schl = w >> 1;                     // which ch_local this wave stages
    const bool sA  = (w & 1) == 0;               // A-side or B-side

    auto stage = [&](int buf, int it) {
        const int ch = ch0 + it * 2 + schl;
        #pragma unroll
        for (int i = 0; i < 8; ++i) {
            const int tt = i >> 1, part = i & 1;
            const short* src = sA
                ? A2f + ((size_t)(bx4 + tt) * 128 + ch + part * 64) * 512 + l * 8
                : Btf + ((size_t)(by4 + tt) * 128 + ch + part * 64) * 512 + l * 8;
            gload_lds16(src, &lds[buf][schl * 16 + (sA ? 0 : 8) + i][0]);
        }
    };

    f32x16 acc[2][2] = {};
    const int wa = (w & 1) * 2;                  // wave's A granule-pair base (tile units)
    const int wb = (w >> 1) * 2;                 // wave's B granule-pair base

    stage(0, 0);
    __syncthreads();

    for (int it = 0; it < 16; ++it) {
        const int cur = it & 1;
        if (it + 1 < 16) stage(cur ^ 1, it + 1);
        #pragma unroll
        for (int chl = 0; chl < 2; ++chl) {
            const int gb = chl * 16;
            bf16x8 a0h = lds[cur][gb + (wa + 0) * 2 + 0][l];
            bf16x8 a0l = lds[cur][gb + (wa + 0) * 2 + 1][l];
            bf16x8 a1h = lds[cur][gb + (wa + 1) * 2 + 0][l];
            bf16x8 a1l = lds[cur][gb + (wa + 1) * 2 + 1][l];
            bf16x8 b0h = lds[cur][gb + 8 + (wb + 0) * 2 + 0][l];
            bf16x8 b0l = lds[cur][gb + 8 + (wb + 0) * 2 + 1][l];
            bf16x8 b1h = lds[cur][gb + 8 + (wb + 1) * 2 + 0][l];
            bf16x8 b1l = lds[cur][gb + 8 + (wb + 1) * 2 + 1][l];
            acc[0][0] = __builtin_amdgcn_mfma_f32_32x32x16_bf16(a0h, b0h, acc[0][0], 0, 0, 0);
            acc[0][1] = __builtin_amdgcn_mfma_f32_32x32x16_bf16(a0h, b1h, acc[0][1], 0, 0, 0);
            acc[1][0] = __builtin_amdgcn_mfma_f32_32x32x16_bf16(a1h, b0h, acc[1][0], 0, 0, 0);
            acc[1][1] = __builtin_amdgcn_mfma_f32_32x32x16_bf16(a1h, b1h, acc[1][1], 0, 0, 0);
            acc[0][0] = __builtin_amdgcn_mfma_f32_32x32x16_bf16(a0h, b0l, acc[0][0], 0, 0, 0);
            acc[0][1] = __builtin_amdgcn_mfma_f32_32x32x16_bf16(a0h, b1l, acc[0][1], 0, 0, 0);
            acc[1][0] = __builtin_amdgcn_mfma_f32_32x32x16_bf16(a1h, b0l, acc[1][0], 0, 0, 0);
            acc[1][1] = __builtin_amdgcn_mfma_f32_32x32x16_bf16(a1h, b1l, acc[1][1], 0, 0, 0);
            acc[0][0] = __builtin_amdgcn_mfma_f32_32x32x16_bf16(a0l, b0h, acc[0][0], 0, 0, 0);
            acc[0][1] = __builtin_amdgcn_mfma_f32_32x32x16_bf16(a0l, b1h, acc[0][1], 0, 0, 0);
            acc[1][0] = __builtin_amdgcn_mfma_f32_32x32x16_bf16(a1l, b0h, acc[1][0], 0, 0, 0);
            acc[1][1] = __builtin_amdgcn_mfma_f32_32x32x16_bf16(a1l, b1h, acc[1][1], 0, 0, 0);
        }
        __syncthreads();                         // drains vmcnt (stage) + lgkm, all waves
    }

    // epilogue: 32x32 C/D layout col=lane&31 (j), row=(reg&3)+8*(reg>>2)+4*(lane>>5)
    float* ptH = kh ? ptB : ptA;
    const int jn = l & 31, hi5 = l >> 5;
    #pragma unroll
    for (int ni = 0; ni < 2; ++ni) {
        const int jt = jt0 + ni;
        if (jt < 27) {                            // tile 27 = pad, fully masked
            const int j = jt * 32 + jn;
            const float bj = (kh == 0) ? bias[j] : 0.f;
            #pragma unroll
            for (int mi = 0; mi < 2; ++mi) {
                #pragma unroll
                for (int q = 0; q < 4; ++q) {     // reg quad q -> rows q*8+hi5*4+0..3
                    f32x4 o;
                    o[0] = acc[mi][ni][q * 4 + 0] + bj;
                    o[1] = acc[mi][ni][q * 4 + 1] + bj;
                    o[2] = acc[mi][ni][q * 4 + 2] + bj;
                    o[3] = acc[mi][ni][q * 4 + 3] + bj;
                    const int s = (mt0 + mi) * 32 + q * 8 + hi5 * 4;
                    *(f32x4*)(ptH + (size_t)j * SEQ + s) = o;
                }
            }
        }
    }
}

// ---------------- 3. Spring recurrence + LDS-window scatter + fused tail ----------------
// R11 structure (3-parity buffers, 1 lgkm wait per 3 macro-steps) unchanged.
// R16's tail fusion kept: this block's (s0+tid, imu) coordinates cover exactly
// 4 output elements of planes 1..4 (noise 8..11); removes a launch + gap.
__global__ __launch_bounds__(256) void spring_kernel(const float* __restrict__ ptA,
                                                     const float* __restrict__ ptB,
                                                     float* __restrict__ out) {
    __shared__ float w3[3][4 * 368];           // 363 used per wave per parity
    const int tid  = threadIdx.x;
    const int lane = tid & 63;
    const int wid  = tid >> 6;
    const int s0   = blockIdx.x * 256;
    const int imu  = blockIdx.y;
    const int s    = s0 + tid;

    // zero own windows (wave-private: no barrier needed before main loop)
    #pragma unroll
    for (int b = 0; b < 3; ++b)
        #pragma unroll
        for (int i = 0; i < 6; ++i) {
            const int idx = lane + i * 64;
            if (idx < 363) w3[b][wid * 368 + idx] = 0.f;
        }

    const int base = imu * SEQ + s;
    const float p0  = ptA[(size_t)0 * PLANE + base] + ptB[(size_t)0 * PLANE + base];
    const float p1  = ptA[(size_t)1 * PLANE + base] + ptB[(size_t)1 * PLANE + base];
    const float p2  = ptA[(size_t)2 * PLANE + base] + ptB[(size_t)2 * PLANE + base];
    const float p3  = ptA[(size_t)3 * PLANE + base] + ptB[(size_t)3 * PLANE + base];
    const float c1  = ptA[(size_t)4 * PLANE + base] + ptB[(size_t)4 * PLANE + base];
    const float c2  = ptA[(size_t)5 * PLANE + base] + ptB[(size_t)5 * PLANE + base];
    const float ph1 = ptA[(size_t)6 * PLANE + base] + ptB[(size_t)6 * PLANE + base];
    const float ph2 = ptA[(size_t)7 * PLANE + base] + ptB[(size_t)7 * PLANE + base];

    float dd = softplus_f(p1);
    float kk = dd * dd * 0.25f + softplus_f(p0);
    float om1 = 0.5f * sqrtf(fmaxf(4.f * kk - dd * dd, 0.f));
    float dt = softplus_f(p3);
    float kt = dt * dt * 0.25f + softplus_f(p2);
    float om2 = 0.5f * sqrtf(fmaxf(4.f * kt - dt * dt, 0.f));
    float e1 = expf(-0.5f * dd), e2 = expf(-0.5f * dt);
    float sn, cs, sn2, cs2;
    sincosf(om1, &sn, &cs);
    sincosf(om2, &sn2, &cs2);
    f32x2 Rr = {e1 * cs, e2 * cs2};          // per-step rotation (packed: osc1, osc2)
    f32x2 Ri = {e1 * sn, e2 * sn2};
    sincosf(ph1, &sn, &cs);
    sincosf(ph2, &sn2, &cs2);
    f32x2 zr = {c1 * cs, c2 * cs2};          // stream A state (t = 0)
    f32x2 zi = {c1 * sn, c2 * sn2};

    // stream B state: z * R^150 (exp-by-squaring)
    f32x2 zrB, ziB;
    {
        f32x2 prr = Rr, pri = Ri;
        f32x2 qr = {1.f, 1.f}, qi = {0.f, 0.f};
        int e = 150;
        while (e) {
            if (e & 1) {
                f32x2 nr = qr * prr - qi * pri;
                qi = qr * pri + qi * prr;
                qr = nr;
            }
            f32x2 nr = prr * prr - pri * pri;
            pri = 2.f * prr * pri;
            prr = nr;
            e >>= 1;
        }
        f32x2 nr = zr * qr - zi * qi;
        ziB = zr * qi + zi * qr;
        zrB = nr;
    }

    float* q0 = &w3[0][wid * 368 + lane];
    float* q1 = &w3[1][wid * 368 + lane];
    float* q2 = &w3[2][wid * 368 + lane];

    #pragma unroll 1
    for (int j = 0; j < 150; j += 3) {
        // values for macro-steps j, j+1, j+2 on both streams
        float vA0 = zi.x + zi.y;
        { f32x2 nr = zr * Rr - zi * Ri; zi = zr * Ri + zi * Rr; zr = nr; }
        float vA1 = zi.x + zi.y;
        { f32x2 nr = zr * Rr - zi * Ri; zi = zr * Ri + zi * Rr; zr = nr; }
        float vA2 = zi.x + zi.y;
        { f32x2 nr = zr * Rr - zi * Ri; zi = zr * Ri + zi * Rr; zr = nr; }
        float vB0 = ziB.x + ziB.y;
        { f32x2 nr = zrB * Rr - ziB * Ri; ziB = zrB * Ri + ziB * Rr; zrB = nr; }
        float vB1 = ziB.x + ziB.y;
        { f32x2 nr = zrB * Rr - ziB * Ri; ziB = zrB * Ri + ziB * Rr; zrB = nr; }
        float vB2 = ziB.x + ziB.y;
        { f32x2 nr = zrB * Rr - ziB * Ri; ziB = zrB * Ri + ziB * Rr; zrB = nr; }

        // all 6 reads issue together -> single lgkm wait per group
        const float a0 = q0[j],     b0 = q0[j + 150];
        const float a1 = q1[j + 1], b1 = q1[j + 151];
        const float a2 = q2[j + 2], b2 = q2[j + 152];
        q0[j]       = a0 + vA0;  q0[j + 150] = b0 + vB0;
        q1[j + 1]   = a1 + vA1;  q1[j + 151] = b1 + vB1;
        q2[j + 2]   = a2 + vA2;  q2[j + 152] = b2 + vB2;
        __asm__ volatile("" ::: "memory");   // pin group order (cross-lane RAW, dist 3)
    }

    // fused tail: noise planes 8..11 -> out planes 1..4 (softplus on odd noise)
    #pragma unroll
    for (int np = 0; np < 4; ++np) {
        float v = ptA[(size_t)(8 + np) * PLANE + base]
                + ptB[(size_t)(8 + np) * PLANE + base];
        if (np & 1) v = softplus_f(v);
        out[(size_t)(np + 1) * PLANE + base] = v;
    }

    __syncthreads();
    // merge 3 parities x 4 wave windows + masked global flush
    for (int i = tid; i < 555; i += 256) {
        float sum = 0.f;
        #pragma unroll
        for (int w = 0; w < 4; ++w) {
            const int idx = i - (w << 6);
            if (idx >= 0 && idx < 363) {
                const int o = w * 368 + idx;
                sum += w3[0][o] + w3[1][o] + w3[2][o];
            }
        }
        const int pos = s0 + i;
        if (pos < SEQ) {
            (void)__hip_atomic_fetch_add(&out[(size_t)imu * SEQ + pos], sum,
                                         __ATOMIC_RELAXED, __HIP_MEMORY_SCOPE_AGENT);
        }
    }
}

extern "C" void kernel_launch(void* const* d_in, const int* in_sizes, int n_in,
                              void* d_out, int out_size, void* d_ws, size_t ws_size,
                              hipStream_t stream) {
    const float* hs    = (const float*)d_in[0];
    const float* gamma = (const float*)d_in[1];
    const float* beta  = (const float*)d_in[2];
    const float* W     = (const float*)d_in[3];
    const float* b     = (const float*)d_in[4];
    float* out = (float*)d_out;

    short* A2f = (short*)d_ws;                        // 16.78 MB
    short* Btf = A2f + A2F_SHORTS;                    //  3.67 MB
    float* ptA = (float*)(Btf + BTF_SHORTS);          // 14.16 MB (split-K half 0 + bias)
    float* ptB = ptA + (size_t)12 * PLANE;            // 14.16 MB (split-K half 1)

    hipMemsetAsync(out, 0, (size_t)PLANE * sizeof(float), stream);

    ln_kernel<<<SEQ / 16, 512, 0, stream>>>(hs, gamma, beta, A2f);
    wprep_kernel<<<dim3(DM / 32, NJ / 32), 256, 0, stream>>>(W, Btf);
    gemm_kernel<<<448, 256, 0, stream>>>(A2f, Btf, b, ptA, ptB);
    spring_kernel<<<dim3(SEQ / 256, NIMU), 256, 0, stream>>>(ptA, ptB, out);
}